// Round 6
// baseline (407.691 us; speedup 1.0000x reference)
//
#include <hip/hip_runtime.h>
#include <cstdint>
#include <cstddef>

#define B_   16
#define N_   2048
#define DN   64
#define DQ   256     // 4*D_NET
#define HID_ 128
#define SEQ_ 18
#define OUTR 2066
#define KVB  32

typedef __attribute__((ext_vector_type(4)))  float f32x4;
typedef __attribute__((ext_vector_type(16))) float f32x16;
typedef __attribute__((ext_vector_type(8)))  short bf16x8;

__device__ __forceinline__ unsigned cvtpk(float lo, float hi) {
  unsigned w;
  asm("v_cvt_pk_bf16_f32 %0, %1, %2" : "=v"(w) : "v"(lo), "v"(hi));
  return w;
}
__device__ __forceinline__ bf16x8 cvt8(const float* p) {
  f32x4 a = *(const f32x4*)p, b = *(const f32x4*)(p + 4);
  union { unsigned u[4]; bf16x8 v; } r;
  r.u[0] = cvtpk(a[0], a[1]); r.u[1] = cvtpk(a[2], a[3]);
  r.u[2] = cvtpk(b[0], b[1]); r.u[3] = cvtpk(b[2], b[3]);
  return r.v;
}
__device__ __forceinline__ float hadd4(f32x4 v) { return (v[0] + v[1]) + (v[2] + v[3]); }

// redistribute 32x32 C-layout rows into B-fragment k-order
__device__ __forceinline__ bf16x8 mkfrag(unsigned wa, unsigned wb,
                                         unsigned wc, unsigned wd, bool hi) {
  unsigned sa = (unsigned)__shfl_xor((int)wa, 32);
  unsigned sb = (unsigned)__shfl_xor((int)wb, 32);
  unsigned sc = (unsigned)__shfl_xor((int)wc, 32);
  unsigned sd = (unsigned)__shfl_xor((int)wd, 32);
  union { unsigned u[4]; bf16x8 v; } r;
  r.u[0] = hi ? sc : wa;
  r.u[1] = hi ? sd : wb;
  r.u[2] = hi ? wc : sa;
  r.u[3] = hi ? wd : sb;
  return r.v;
}

// ======================= proj + sfc kernel (512 threads) =======================
struct SfcS {
  float xs[SEQ_][132];
  float qkv[SEQ_][388];
  float scs[4][SEQ_][19];
  float sinb[SEQ_][32];
  float ffh[SEQ_][8];
  float maskv[SEQ_];
};
union PSmem { short wl[16384]; SfcS sfc; };   // 32KB weight buffer / 45.9KB sfc

// proj: 8 waves x 16 rows = 128 rows/block; ONE weight matrix staged at a time (32KB)
__device__ void proj_body(int gid, short* wl,
    const float* __restrict__ net, const float* __restrict__ Wq, const float* __restrict__ bq,
    const float* __restrict__ Wk, const float* __restrict__ bk,
    const float* __restrict__ Wv, const float* __restrict__ bv,
    short* __restrict__ Qb, short* __restrict__ Kb, short* __restrict__ Vt) {
  const int b = gid >> 4;
  const int r0 = (gid & 15) * 128;
  const int t = threadIdx.x;
  const int w = t >> 6, lane = t & 63, ln = lane & 15, g = lane >> 4;
  const int rw = r0 + w * 16;
  const int xk = (ln & 7) << 4;

  bf16x8 af[2];
#pragma unroll
  for (int c = 0; c < 2; ++c)
    af[c] = cvt8(net + ((size_t)b * N_ + rw + ln) * DN + c * 32 + g * 8);

  const float* Ws[3] = {Wq, Wk, Wv};
  for (int m = 0; m < 3; ++m) {
    __syncthreads();
#pragma unroll
    for (int it = 0; it < 8; ++it) {           // 4096 f32x4 quads, 512 threads
      int idx = it * 512 + t;
      int row = idx >> 4, c8 = idx & 15;
      f32x4 v = *(const f32x4*)(Ws[m] + row * 64 + c8 * 4);
      int byo = row * 128 + ((c8 * 8) ^ ((row & 7) << 4));
      *(uint2*)((char*)wl + byo) = make_uint2(cvtpk(v[0], v[1]), cvtpk(v[2], v[3]));
    }
    __syncthreads();
    if (m < 2) {
      const float* bias = (m == 0) ? bq : bk;
      short* dst = (m == 0) ? Qb : Kb;
      const float sc = (m == 0) ? 0.125f : 1.0f;   // fold 1/sqrt(64) into Q
#pragma unroll
      for (int tt = 0; tt < 16; ++tt) {
        f32x4 acc = {0.f, 0.f, 0.f, 0.f};
#pragma unroll
        for (int c = 0; c < 2; ++c) {
          int byo = (tt * 16 + ln) * 128 + ((c * 64 + g * 16) ^ xk);
          bf16x8 wf = *(const bf16x8*)((char*)wl + byo);
          acc = __builtin_amdgcn_mfma_f32_16x16x32_bf16(wf, af[c], acc, 0, 0, 0);
        }
        f32x4 b4 = *(const f32x4*)(bias + tt * 16 + g * 4);
        uint2 u = make_uint2(cvtpk((acc[0] + b4[0]) * sc, (acc[1] + b4[1]) * sc),
                             cvtpk((acc[2] + b4[2]) * sc, (acc[3] + b4[3]) * sc));
        *(uint2*)(dst + ((size_t)b * N_ + rw + ln) * DQ + tt * 16 + g * 4) = u;
      }
    } else {
#pragma unroll
      for (int tt = 0; tt < 16; ++tt) {
        f32x4 acc = {0.f, 0.f, 0.f, 0.f};
#pragma unroll
        for (int c = 0; c < 2; ++c) {
          int byo = (tt * 16 + ln) * 128 + ((c * 64 + g * 16) ^ xk);
          bf16x8 wf = *(const bf16x8*)((char*)wl + byo);
          acc = __builtin_amdgcn_mfma_f32_16x16x32_bf16(af[c], wf, acc, 0, 0, 0);
        }
        float bias = bv[tt * 16 + ln];
        uint2 u = make_uint2(cvtpk(acc[0] + bias, acc[1] + bias),
                             cvtpk(acc[2] + bias, acc[3] + bias));
        *(uint2*)(Vt + ((size_t)b * DQ + tt * 16 + ln) * N_ + rw + g * 4) = u;
      }
    }
  }
}

// parallel layernorm: input qkv[.][128..256) -> xs ; 8 waves
__device__ __forceinline__ void par_ln(SfcS& S, const float* __restrict__ lw,
                                       const float* __restrict__ lb, int w, int lane) {
  float w0 = lw[lane * 2], w1 = lw[lane * 2 + 1];
  float b0 = lb[lane * 2], b1 = lb[lane * 2 + 1];
  for (int r = w; r < SEQ_; r += 8) {
    float2 v = *(const float2*)&S.qkv[r][128 + lane * 2];
    float s1 = v.x + v.y;
    float s2 = v.x * v.x + v.y * v.y;
#pragma unroll
    for (int off = 1; off < 64; off <<= 1) {
      s1 += __shfl_xor(s1, off);
      s2 += __shfl_xor(s2, off);
    }
    float mu = s1 * 0.0078125f;
    float var = s2 * 0.0078125f - mu * mu;
    float rsd = rsqrtf(var + 1e-5f);
    S.xs[r][lane * 2]     = (v.x - mu) * rsd * w0 + b0;
    S.xs[r][lane * 2 + 1] = (v.y - mu) * rsd * w1 + b1;
  }
}

// sfc: one batch per block, 512 threads (2 waves/SIMD)
__device__ void sfc_body(
    int b, SfcS& S,
    const float* __restrict__ sfc_state, const int* __restrict__ node_pair,
    const float* __restrict__ node_embed, const float* __restrict__ sfcW,
    const float* __restrict__ sfcb, const float* __restrict__ pos,
    const float* __restrict__ qkvW, const float* __restrict__ qkvB,
    const float* __restrict__ outW, const float* __restrict__ outB,
    const float* __restrict__ ln1w, const float* __restrict__ ln1b,
    const float* __restrict__ l1w, const float* __restrict__ l1b,
    const float* __restrict__ l2w, const float* __restrict__ l2b,
    const float* __restrict__ ln2w, const float* __restrict__ ln2b,
    float* __restrict__ out) {
  const int t = threadIdx.x;          // 0..511
  const int w = t >> 6, lane = t & 63;

  for (int i = t; i < SEQ_ * 32; i += 512) {
    int s = i >> 5, d = i & 31;
    float v;
    if (s == 0)       v = node_embed[node_pair[b * 2 + 0] * 32 + d];
    else if (s == 17) v = node_embed[node_pair[b * 2 + 1] * 32 + d];
    else              v = sfc_state[((size_t)b * 16 + (s - 1)) * 32 + d];
    S.sinb[s][d] = v;
  }
  __syncthreads();
  if (t < SEQ_) {
    float sum = 0.f;
#pragma unroll
    for (int d = 0; d < 32; ++d) sum += fabsf(S.sinb[t][d]);
    S.maskv[t] = (sum == 0.f) ? -1e9f : 0.f;
  }
  {
    int hh = t & 127, part = t >> 7;     // 4 parts x 128 h
    f32x4 wr[8];
#pragma unroll
    for (int j = 0; j < 8; ++j) wr[j] = *(const f32x4*)(sfcW + hh * 32 + j * 4);
    for (int si = part; si < SEQ_; si += 4) {
      f32x4 a = {0.f, 0.f, 0.f, 0.f};
#pragma unroll
      for (int j = 0; j < 8; ++j) a += wr[j] * (*(const f32x4*)&S.sinb[si][j * 4]);
      S.xs[si][hh] = hadd4(a) + sfcb[hh] + pos[si * HID_ + hh];
    }
  }
  __syncthreads();

  for (int ll = 0; ll < 2; ++ll) {
    // qkv = x @ W^T + b  (384 outputs; ILP via f32x4 partials per s)
    if (t < 384) {
      const float* wp = qkvW + ((size_t)ll * 384 + t) * HID_;
      f32x4 acc4[SEQ_];
#pragma unroll
      for (int s = 0; s < SEQ_; ++s) acc4[s] = (f32x4){0.f, 0.f, 0.f, 0.f};
      for (int kb = 0; kb < 4; ++kb) {
        f32x4 wv[8];
#pragma unroll
        for (int j = 0; j < 8; ++j) wv[j] = *(const f32x4*)(wp + kb * 32 + j * 4);
#pragma unroll
        for (int s = 0; s < SEQ_; ++s) {
#pragma unroll
          for (int j = 0; j < 8; ++j)
            acc4[s] += wv[j] * (*(const f32x4*)&S.xs[s][kb * 32 + j * 4]);
        }
      }
      float bias = qkvB[ll * 384 + t];
#pragma unroll
      for (int s = 0; s < SEQ_; ++s) S.qkv[s][t] = hadd4(acc4[s]) + bias;
    }
    __syncthreads();
    for (int i = t; i < 4 * SEQ_ * SEQ_; i += 512) {
      int hh = i / (SEQ_ * SEQ_), rem = i - hh * SEQ_ * SEQ_;
      int qi = rem / SEQ_, kj = rem - qi * SEQ_;
      f32x4 a = {0.f, 0.f, 0.f, 0.f};
#pragma unroll
      for (int j = 0; j < 8; ++j)
        a += (*(const f32x4*)&S.qkv[qi][hh * 32 + j * 4]) *
             (*(const f32x4*)&S.qkv[kj][128 + hh * 32 + j * 4]);
      S.scs[hh][qi][kj] = hadd4(a) * 0.17677669529663687f + S.maskv[kj];
    }
    __syncthreads();
    if (t < 4 * SEQ_) {
      int hh = t / SEQ_, qi = t - hh * SEQ_;
      float mx = -1e30f;
#pragma unroll
      for (int j = 0; j < SEQ_; ++j) mx = fmaxf(mx, S.scs[hh][qi][j]);
      float sum = 0.f;
#pragma unroll
      for (int j = 0; j < SEQ_; ++j) {
        float e = __expf(S.scs[hh][qi][j] - mx);
        S.scs[hh][qi][j] = e; sum += e;
      }
      float inv = 1.f / sum;
#pragma unroll
      for (int j = 0; j < SEQ_; ++j) S.scs[hh][qi][j] *= inv;
    }
    __syncthreads();
    for (int i = t; i < SEQ_ * HID_; i += 512) {
      int s = i >> 7, hd = i & 127, hh = hd >> 5;
      float a = 0.f;
#pragma unroll
      for (int j = 0; j < SEQ_; ++j) a += S.scs[hh][s][j] * S.qkv[j][256 + hd];
      S.qkv[s][hd] = a;
    }
    __syncthreads();
    {
      int hh = t & 127, part = t >> 7;
      const float* wp = outW + ((size_t)ll * HID_ + hh) * HID_;
      f32x4 a4[5];
#pragma unroll
      for (int r = 0; r < 5; ++r) a4[r] = (f32x4){0.f, 0.f, 0.f, 0.f};
      for (int kb = 0; kb < 4; ++kb) {
        f32x4 wv[8];
#pragma unroll
        for (int j = 0; j < 8; ++j) wv[j] = *(const f32x4*)(wp + kb * 32 + j * 4);
#pragma unroll
        for (int r = 0; r < 5; ++r) {
          int si = part + r * 4;
          if (si < SEQ_) {
#pragma unroll
            for (int j = 0; j < 8; ++j)
              a4[r] += wv[j] * (*(const f32x4*)&S.qkv[si][kb * 32 + j * 4]);
          }
        }
      }
      float bias = outB[ll * HID_ + hh];
#pragma unroll
      for (int r = 0; r < 5; ++r) {
        int si = part + r * 4;
        if (si < SEQ_)
          S.qkv[si][128 + hh] = S.xs[si][hh] + hadd4(a4[r]) + bias;
      }
    }
    __syncthreads();
    par_ln(S, ln1w + ll * HID_, ln1b + ll * HID_, w, lane);
    __syncthreads();
    if (t < SEQ_ * 8) {
      int s = t >> 3, oo = t & 7;
      const float* wp = l1w + ((size_t)ll * 8 + oo) * HID_;
      f32x4 a = {0.f, 0.f, 0.f, 0.f};
#pragma unroll
      for (int j = 0; j < 32; ++j)
        a += (*(const f32x4*)(wp + j * 4)) * (*(const f32x4*)&S.xs[s][j * 4]);
      S.ffh[s][oo] = fmaxf(hadd4(a) + l1b[ll * 8 + oo], 0.f);
    }
    __syncthreads();
    for (int i = t; i < SEQ_ * HID_; i += 512) {
      int s = i >> 7, h2 = i & 127;
      const float* wp = l2w + ((size_t)ll * HID_ + h2) * 8;
      float a = 0.f;
#pragma unroll
      for (int j = 0; j < 8; ++j) a += wp[j] * S.ffh[s][j];
      S.qkv[s][128 + h2] = S.xs[s][h2] + a + l2b[ll * HID_ + h2];
    }
    __syncthreads();
    par_ln(S, ln2w + ll * HID_, ln2b + ll * HID_, w, lane);
    __syncthreads();
  }
  for (int i = t; i < SEQ_ * HID_; i += 512) {
    int s = i >> 7, h2 = i & 127;
    out[((size_t)b * OUTR + 2048 + s) * HID_ + h2] = S.xs[s][h2];
  }
}

__global__ __launch_bounds__(512, 2) void proj_sfc_kernel(
    const float* __restrict__ net, const float* __restrict__ Wq, const float* __restrict__ bq,
    const float* __restrict__ Wk, const float* __restrict__ bk,
    const float* __restrict__ Wv, const float* __restrict__ bv,
    short* __restrict__ Qb, short* __restrict__ Kb, short* __restrict__ Vt,
    const float* __restrict__ sfc_state, const int* __restrict__ node_pair,
    const float* __restrict__ node_embed, const float* __restrict__ sfcW,
    const float* __restrict__ sfcb, const float* __restrict__ pos,
    const float* __restrict__ qkvW, const float* __restrict__ qkvB,
    const float* __restrict__ outW, const float* __restrict__ outB,
    const float* __restrict__ ln1w, const float* __restrict__ ln1b,
    const float* __restrict__ l1w, const float* __restrict__ l1b,
    const float* __restrict__ l2w, const float* __restrict__ l2b,
    const float* __restrict__ ln2w, const float* __restrict__ ln2b,
    float* __restrict__ out) {
  __shared__ PSmem sm;
  if (blockIdx.x < 16) {
    sfc_body(blockIdx.x, sm.sfc, sfc_state, node_pair, node_embed, sfcW, sfcb, pos,
             qkvW, qkvB, outW, outB, ln1w, ln1b, l1w, l1b, l2w, l2b, ln2w, ln2b, out);
  } else {
    proj_body(blockIdx.x - 16, sm.wl, net, Wq, bq, Wk, bk, Wv, bv, Qb, Kb, Vt);
  }
}

// ======================= attention: 512 blocks x 4 waves, kv split-2 =======================
__global__ __launch_bounds__(256, 2) void attn_kernel(
    const short* __restrict__ Qb, const short* __restrict__ Kb,
    const short* __restrict__ Vt,
    const float* __restrict__ netW, const float* __restrict__ netb,
    short* __restrict__ Op, float* __restrict__ Ls, int* __restrict__ flags,
    float* __restrict__ out) {
  __shared__ char smem[49152];     // K dbuf 32KB + V 16KB
  __shared__ int lastf;

  const int bid = blockIdx.x;
  const int b = (bid & 7) * 2 + ((bid >> 3) & 1);   // batch <-> XCD affinity
  const int rest = bid >> 4;                        // 0..31
  const int qtile = rest & 15;
  const int half = rest >> 4;                       // kv half
  const int q0 = qtile * 128;
  const int t = threadIdx.x;
  const int w = t >> 6, l = t & 63;
  const int l31 = l & 31, h = l >> 5, l7 = l & 7;
  const int qw = q0 + w * 32;
  const bool hb = (h != 0);

  const short* Kg = Kb + ((size_t)b * N_ + (size_t)half * 1024) * DQ;
  const short* Vg = Vt + (size_t)b * DQ * N_;       // + half*2048 + tile*64 cols
  char* kb0  = smem;
  char* kb1  = smem + 16384;
  char* vbuf = smem + 32768;

  bf16x8 qf[16];
  const short* Qrow = Qb + ((size_t)b * N_ + qw + l31) * DQ + h * 8;
#pragma unroll
  for (int kc = 0; kc < 16; ++kc)
    qf[kc] = *(const bf16x8*)(Qrow + kc * 16);

  f32x16 o[8];
#pragma unroll
  for (int dt = 0; dt < 8; ++dt)
#pragma unroll
    for (int r = 0; r < 16; ++r) o[dt][r] = 0.f;
  float lsum = 0.f;

  auto stage_k = [&](int tile, char* dst) {
#pragma unroll
    for (int it = 0; it < 4; ++it) {
      int i = w * 4 + it;
      int row = i * 2 + h;
      int gcol = (l31 * 16) ^ ((row & 7) << 4);
      const char* src = (const char*)(Kg + (size_t)(tile * KVB + row) * DQ) + gcol;
      __builtin_amdgcn_global_load_lds(
          (const __attribute__((address_space(1))) void*)src,
          (__attribute__((address_space(3))) void*)(dst + i * 1024), 16, 0, 0);
    }
  };
  bf16x8 vreg[4];
  auto load_v = [&](int tile) {
#pragma unroll
    for (int it = 0; it < 4; ++it) {
      int i = w * 4 + it;
      int row = i * 16 + (l >> 2);
      int gcol = (((l & 3) << 4)) ^ (((row >> 1) & 3) << 4);   // bank-fixed swizzle
      vreg[it] = *(const bf16x8*)((const char*)(Vg + (size_t)row * N_) +
                                  half * 2048 + tile * (KVB * 2) + gcol);
    }
  };
  auto write_v = [&]() {
#pragma unroll
    for (int it = 0; it < 4; ++it) {
      int i = w * 4 + it;
      *(bf16x8*)(vbuf + i * 1024 + l * 16) = vreg[it];
    }
  };

  stage_k(0, kb0);
  load_v(0);
  __syncthreads();
  write_v();
  __syncthreads();

  const int vswz = ((l31 >> 1) & 3) << 4;
  for (int tt = 0; tt < 32; ++tt) {
    char* kc_ = (tt & 1) ? kb1 : kb0;
    if (tt < 31) {
      stage_k(tt + 1, (tt & 1) ? kb0 : kb1);
      load_v(tt + 1);
    }
    // QK^T (swapped: S^T[32 kv][32 q], q lane-local)
    f32x16 s;
#pragma unroll
    for (int r = 0; r < 16; ++r) s[r] = 0.f;
    __builtin_amdgcn_s_setprio(1);
#pragma unroll
    for (int kc = 0; kc < 16; ++kc) {
      bf16x8 kf = *(const bf16x8*)(kc_ + l31 * 512 + ((kc * 32 + h * 16) ^ (l7 << 4)));
      s = __builtin_amdgcn_mfma_f32_32x32x16_bf16(kf, qf[kc], s, 0, 0, 0);
    }
    __builtin_amdgcn_s_setprio(0);
    // softmax m=0 (|scores| bounded small; exact)
#pragma unroll
    for (int r = 0; r < 16; ++r) { s[r] = __expf(s[r]); lsum += s[r]; }
    unsigned wA = cvtpk(s[0], s[1]),   wB = cvtpk(s[2], s[3]);
    unsigned wC = cvtpk(s[4], s[5]),   wD = cvtpk(s[6], s[7]);
    unsigned wE = cvtpk(s[8], s[9]),   wF = cvtpk(s[10], s[11]);
    unsigned wG = cvtpk(s[12], s[13]), wH = cvtpk(s[14], s[15]);
    bf16x8 pf0 = mkfrag(wA, wB, wC, wD, hb);
    bf16x8 pf1 = mkfrag(wE, wF, wG, wH, hb);
    // PV: O^T[256 d][32 q]
    __builtin_amdgcn_s_setprio(1);
#pragma unroll
    for (int dt = 0; dt < 8; ++dt) {
      const char* vrow = vbuf + (dt * 32 + l31) * 64;
      bf16x8 v0 = *(const bf16x8*)(vrow + ((h * 16) ^ vswz));
      bf16x8 v1 = *(const bf16x8*)(vrow + ((32 + h * 16) ^ vswz));
      o[dt] = __builtin_amdgcn_mfma_f32_32x32x16_bf16(v0, pf0, o[dt], 0, 0, 0);
      o[dt] = __builtin_amdgcn_mfma_f32_32x32x16_bf16(v1, pf1, o[dt], 0, 0, 0);
    }
    __builtin_amdgcn_s_setprio(0);
    __syncthreads();               // all reads of current tile done (+drain prefetch)
    if (tt < 31) write_v();
    __syncthreads();               // next tile published
  }

  lsum += __shfl_xor(lsum, 32);

  // ---- write partial (bf16 fragments, raw lane layout) ----
  const size_t slot = (((size_t)half * 16 + b) * 16 + qtile) * 4 + w;
  short* opb = Op + slot * 8192 + (size_t)l * 16;
#pragma unroll
  for (int dt = 0; dt < 8; ++dt) {
    uint4 u0, u1;
    u0.x = cvtpk(o[dt][0],  o[dt][1]);  u0.y = cvtpk(o[dt][2],  o[dt][3]);
    u0.z = cvtpk(o[dt][4],  o[dt][5]);  u0.w = cvtpk(o[dt][6],  o[dt][7]);
    u1.x = cvtpk(o[dt][8],  o[dt][9]);  u1.y = cvtpk(o[dt][10], o[dt][11]);
    u1.z = cvtpk(o[dt][12], o[dt][13]); u1.w = cvtpk(o[dt][14], o[dt][15]);
    *(uint4*)(opb + dt * 1024)     = u0;
    *(uint4*)(opb + dt * 1024 + 8) = u1;
  }
  if (l < 32) Ls[slot * 32 + l31] = lsum;

  __threadfence();
  if (t == 0) lastf = atomicAdd(&flags[b * 16 + qtile], 1);
  __syncthreads();
  if (lastf == 0) return;          // partner will combine
  __threadfence();                 // acquire partner's writes

  // ---- combine: own(bf16-rounded) + partner(bf16) ----
  const size_t pslot = (((size_t)(half ^ 1) * 16 + b) * 16 + qtile) * 4 + w;
  const short* ppb = Op + pslot * 8192 + (size_t)l * 16;
  float ltot = lsum + Ls[pslot * 32 + l31];
#pragma unroll
  for (int dt = 0; dt < 8; ++dt) {
    uint4 p0 = *(const uint4*)(ppb + dt * 1024);
    uint4 p1 = *(const uint4*)(ppb + dt * 1024 + 8);
    unsigned pw[8] = {p0.x, p0.y, p0.z, p0.w, p1.x, p1.y, p1.z, p1.w};
#pragma unroll
    for (int k = 0; k < 8; ++k) {
      unsigned ow = cvtpk(o[dt][2 * k], o[dt][2 * k + 1]);
      o[dt][2 * k]     = __uint_as_float(ow << 16) + __uint_as_float(pw[k] << 16);
      o[dt][2 * k + 1] = __uint_as_float(ow & 0xffff0000u) +
                         __uint_as_float(pw[k] & 0xffff0000u);
    }
  }

  const float linv = 1.f / ltot;
  bf16x8 of[16];
#pragma unroll
  for (int dt = 0; dt < 8; ++dt) {
    unsigned a0 = cvtpk(o[dt][0] * linv,  o[dt][1] * linv);
    unsigned a1 = cvtpk(o[dt][2] * linv,  o[dt][3] * linv);
    unsigned a2 = cvtpk(o[dt][4] * linv,  o[dt][5] * linv);
    unsigned a3 = cvtpk(o[dt][6] * linv,  o[dt][7] * linv);
    unsigned a4 = cvtpk(o[dt][8] * linv,  o[dt][9] * linv);
    unsigned a5 = cvtpk(o[dt][10] * linv, o[dt][11] * linv);
    unsigned a6 = cvtpk(o[dt][12] * linv, o[dt][13] * linv);
    unsigned a7 = cvtpk(o[dt][14] * linv, o[dt][15] * linv);
    of[dt * 2]     = mkfrag(a0, a1, a2, a3, hb);
    of[dt * 2 + 1] = mkfrag(a4, a5, a6, a7, hb);
  }
  // fused out-projection: out^T[128][q] = netW @ O
  float* orow = out + ((size_t)b * OUTR + qw + l31) * HID_;
#pragma unroll
  for (int ot = 0; ot < 4; ++ot) {
    f32x16 acc;
#pragma unroll
    for (int r = 0; r < 16; ++r) acc[r] = 0.f;
#pragma unroll
    for (int dc = 0; dc < 16; ++dc) {
      const float* wp = netW + (size_t)(ot * 32 + l31) * DQ + dc * 16 + h * 8;
      f32x4 w0 = *(const f32x4*)wp;
      f32x4 w1 = *(const f32x4*)(wp + 4);
      union { unsigned u[4]; bf16x8 v; } nf;
      nf.u[0] = cvtpk(w0[0], w0[1]); nf.u[1] = cvtpk(w0[2], w0[3]);
      nf.u[2] = cvtpk(w1[0], w1[1]); nf.u[3] = cvtpk(w1[2], w1[3]);
      acc = __builtin_amdgcn_mfma_f32_32x32x16_bf16(nf.v, of[dc], acc, 0, 0, 0);
    }
#pragma unroll
    for (int rq = 0; rq < 4; ++rq) {
      f32x4 bia = *(const f32x4*)(netb + ot * 32 + rq * 8 + h * 4);
      f32x4 vv;
      vv[0] = acc[4 * rq + 0] + bia[0];
      vv[1] = acc[4 * rq + 1] + bia[1];
      vv[2] = acc[4 * rq + 2] + bia[2];
      vv[3] = acc[4 * rq + 3] + bia[3];
      *(f32x4*)(orow + ot * 32 + rq * 8 + h * 4) = vv;
    }
  }
}

extern "C" void kernel_launch(void* const* d_in, const int* in_sizes, int n_in,
                              void* d_out, int out_size, void* d_ws, size_t ws_size,
                              hipStream_t stream) {
  (void)in_sizes; (void)n_in; (void)out_size; (void)ws_size;
  const float* net_state  = (const float*)d_in[0];
  const float* sfc_state  = (const float*)d_in[1];
  const int*   node_pair  = (const int*)d_in[2];
  const float* Wq   = (const float*)d_in[3];
  const float* bq   = (const float*)d_in[4];
  const float* Wk   = (const float*)d_in[5];
  const float* bk   = (const float*)d_in[6];
  const float* Wv   = (const float*)d_in[7];
  const float* bv   = (const float*)d_in[8];
  const float* netW = (const float*)d_in[9];
  const float* netb = (const float*)d_in[10];
  const float* node_embed = (const float*)d_in[11];
  const float* sfcW = (const float*)d_in[12];
  const float* sfcb = (const float*)d_in[13];
  const float* pos  = (const float*)d_in[14];
  const float* qkvW = (const float*)d_in[15];
  const float* qkvB = (const float*)d_in[16];
  const float* outW = (const float*)d_in[17];
  const float* outB = (const float*)d_in[18];
  const float* ln1w = (const float*)d_in[19];
  const float* ln1b = (const float*)d_in[20];
  const float* l1w  = (const float*)d_in[21];
  const float* l1b  = (const float*)d_in[22];
  const float* l2w  = (const float*)d_in[23];
  const float* l2b  = (const float*)d_in[24];
  const float* ln2w = (const float*)d_in[25];
  const float* ln2b = (const float*)d_in[26];
  float* out = (float*)d_out;

  const size_t S = (size_t)B_ * N_ * DQ;       // 8,388,608 shorts
  short* Qb = (short*)d_ws;
  short* Kb = Qb + S;
  short* Vt = Kb + S;
  short* Op = Vt + S;                          // 16,777,216 shorts
  float* Ls = (float*)(Op + (size_t)16777216); // 65,536 floats
  int* flags = (int*)(Ls + 65536);             // 256 ints

  hipMemsetAsync(flags, 0, 256 * sizeof(int), stream);
  proj_sfc_kernel<<<272, 512, 0, stream>>>(net_state, Wq, bq, Wk, bk, Wv, bv, Qb, Kb, Vt,
                                           sfc_state, node_pair, node_embed, sfcW, sfcb, pos,
                                           qkvW, qkvB, outW, outB, ln1w, ln1b, l1w, l1b,
                                           l2w, l2b, ln2w, ln2b, out);
  attn_kernel<<<512, 256, 0, stream>>>(Qb, Kb, Vt, netW, netb, Op, Ls, flags, out);
}

// Round 7
// 184.400 us; speedup vs baseline: 2.2109x; 2.2109x over previous
//
#include <hip/hip_runtime.h>
#include <cstdint>
#include <cstddef>

#define B_   16
#define N_   2048
#define DN   64
#define DQ   256     // 4*D_NET
#define HID_ 128
#define SEQ_ 18
#define OUTR 2066
#define KVB  32

typedef __attribute__((ext_vector_type(4)))  float f32x4;
typedef __attribute__((ext_vector_type(16))) float f32x16;
typedef __attribute__((ext_vector_type(8)))  short bf16x8;

__device__ __forceinline__ unsigned cvtpk(float lo, float hi) {
  unsigned w;
  asm("v_cvt_pk_bf16_f32 %0, %1, %2" : "=v"(w) : "v"(lo), "v"(hi));
  return w;
}
__device__ __forceinline__ short f2bf(float f) {
  union { float f; unsigned u; } v; v.f = f;
  unsigned r = v.u + 0x7fffu + ((v.u >> 16) & 1u);
  return (short)(r >> 16);
}
__device__ __forceinline__ bf16x8 cvt8(const float* p) {
  f32x4 a = *(const f32x4*)p, b = *(const f32x4*)(p + 4);
  union { unsigned u[4]; bf16x8 v; } r;
  r.u[0] = cvtpk(a[0], a[1]); r.u[1] = cvtpk(a[2], a[3]);
  r.u[2] = cvtpk(b[0], b[1]); r.u[3] = cvtpk(b[2], b[3]);
  return r.v;
}
__device__ __forceinline__ float hadd4(f32x4 v) { return (v[0] + v[1]) + (v[2] + v[3]); }

// redistribute 32x32 C-layout rows into MFMA-fragment k-order (A or B frag)
__device__ __forceinline__ bf16x8 mkfrag(unsigned wa, unsigned wb,
                                         unsigned wc, unsigned wd, bool hi) {
  unsigned sa = (unsigned)__shfl_xor((int)wa, 32);
  unsigned sb = (unsigned)__shfl_xor((int)wb, 32);
  unsigned sc = (unsigned)__shfl_xor((int)wc, 32);
  unsigned sd = (unsigned)__shfl_xor((int)wd, 32);
  union { unsigned u[4]; bf16x8 v; } r;
  r.u[0] = hi ? sc : wa;
  r.u[1] = hi ? sd : wb;
  r.u[2] = hi ? wc : sa;
  r.u[3] = hi ? wd : sb;
  return r.v;
}

// ======================= proj kernel: Q, K, and G = netW·V^T frags =======================
__global__ __launch_bounds__(512) void proj_kernel(
    const float* __restrict__ net, const float* __restrict__ Wq, const float* __restrict__ bq,
    const float* __restrict__ Wk, const float* __restrict__ bk,
    const float* __restrict__ Wv, const float* __restrict__ bv,
    const float* __restrict__ netW,
    short* __restrict__ Qb, short* __restrict__ Kb, short* __restrict__ Gf) {
  __shared__ char psm[98304];          // wl 32KB | Vrm 64KB (bf16 [128 n][256 d] swizzled)
  short* wl = (short*)psm;
  char* vrm = psm + 32768;

  const int gid = blockIdx.x;
  const int b = gid >> 4;
  const int r0 = (gid & 15) * 128;
  const int t = threadIdx.x;
  const int w = t >> 6, lane = t & 63, ln = lane & 15, g = lane >> 4;
  const int rw = r0 + w * 16;
  const int xk = (ln & 7) << 4;

  bf16x8 af[2];
#pragma unroll
  for (int c = 0; c < 2; ++c)
    af[c] = cvt8(net + ((size_t)b * N_ + rw + ln) * DN + c * 32 + g * 8);

  const float* Ws[3] = {Wq, Wk, Wv};
  for (int m = 0; m < 3; ++m) {
    __syncthreads();
#pragma unroll
    for (int it = 0; it < 8; ++it) {         // stage W[m] 256x64 f32 -> bf16 swizzled
      int idx = it * 512 + t;
      int row = idx >> 4, c8 = idx & 15;
      f32x4 v = *(const f32x4*)(Ws[m] + row * 64 + c8 * 4);
      int byo = row * 128 + ((c8 * 8) ^ ((row & 7) << 4));
      *(uint2*)((char*)wl + byo) = make_uint2(cvtpk(v[0], v[1]), cvtpk(v[2], v[3]));
    }
    __syncthreads();
    if (m < 2) {
      const float* bias = (m == 0) ? bq : bk;
      short* dst = (m == 0) ? Qb : Kb;
      const float sc = (m == 0) ? 0.125f : 1.0f;   // fold 1/sqrt(64) into Q
#pragma unroll
      for (int tt = 0; tt < 16; ++tt) {
        f32x4 acc = {0.f, 0.f, 0.f, 0.f};
#pragma unroll
        for (int c = 0; c < 2; ++c) {
          int byo = (tt * 16 + ln) * 128 + ((c * 64 + g * 16) ^ xk);
          bf16x8 wf = *(const bf16x8*)((char*)wl + byo);
          acc = __builtin_amdgcn_mfma_f32_16x16x32_bf16(wf, af[c], acc, 0, 0, 0);
        }
        f32x4 b4 = *(const f32x4*)(bias + tt * 16 + g * 4);
        uint2 u = make_uint2(cvtpk((acc[0] + b4[0]) * sc, (acc[1] + b4[1]) * sc),
                             cvtpk((acc[2] + b4[2]) * sc, (acc[3] + b4[3]) * sc));
        *(uint2*)(dst + ((size_t)b * N_ + rw + ln) * DQ + tt * 16 + g * 4) = u;
      }
    } else {
      // V tile -> bf16 row-major in LDS (Vrm[nn][d], 512B rows, XOR swizzle)
#pragma unroll
      for (int tt = 0; tt < 16; ++tt) {
        f32x4 acc = {0.f, 0.f, 0.f, 0.f};
#pragma unroll
        for (int c = 0; c < 2; ++c) {
          int byo = (tt * 16 + ln) * 128 + ((c * 64 + g * 16) ^ xk);
          bf16x8 wf = *(const bf16x8*)((char*)wl + byo);
          acc = __builtin_amdgcn_mfma_f32_16x16x32_bf16(af[c], wf, acc, 0, 0, 0);
        }
        float bias = bv[tt * 16 + ln];
        int d = tt * 16 + ln;
#pragma unroll
        for (int r = 0; r < 4; ++r) {
          int nn = w * 16 + g * 4 + r;
          int byte = nn * 512 + ((d * 2) ^ ((nn & 7) << 4));
          *(short*)(vrm + byte) = f2bf(acc[r] + bias);
        }
      }
    }
  }
  __syncthreads();

  // ---- G phase: G^T tiles C[n][d'] = V[n][:]·netW[d'][:]; mkfrag -> PV A-frags ----
  const int l31 = lane & 31, h = lane >> 5;
  const bool hb = (h != 0);
#pragma unroll
  for (int j = 0; j < 2; ++j) {
    int ti = w * 2 + j;
    int nt = ti >> 2, dt = ti & 3;
    f32x16 C;
#pragma unroll
    for (int r = 0; r < 16; ++r) C[r] = 0.f;
    int n = nt * 32 + l31;
#pragma unroll
    for (int dc = 0; dc < 16; ++dc) {
      bf16x8 A = *(const bf16x8*)(vrm + n * 512 + ((dc * 32 + h * 16) ^ ((n & 7) << 4)));
      bf16x8 Bf = cvt8(netW + (size_t)(dt * 32 + l31) * DQ + dc * 16 + h * 8);
      C = __builtin_amdgcn_mfma_f32_32x32x16_bf16(A, Bf, C, 0, 0, 0);
    }
    unsigned a0 = cvtpk(C[0],  C[1]),  a1 = cvtpk(C[2],  C[3]);
    unsigned a2 = cvtpk(C[4],  C[5]),  a3 = cvtpk(C[6],  C[7]);
    unsigned a4 = cvtpk(C[8],  C[9]),  a5 = cvtpk(C[10], C[11]);
    unsigned a6 = cvtpk(C[12], C[13]), a7 = cvtpk(C[14], C[15]);
    bf16x8 f0 = mkfrag(a0, a1, a2, a3, hb);   // k = n 0..15
    bf16x8 f1 = mkfrag(a4, a5, a6, a7, hb);   // k = n 16..31
    size_t base = (((size_t)b * 64 + (r0 >> 5) + nt) * 8 + dt * 2) * 512;
    *(bf16x8*)(Gf + base + lane * 8)       = f0;
    *(bf16x8*)(Gf + base + 512 + lane * 8) = f1;
  }
}

// ======================= sfc (r4-verified 256-thread body) =======================
struct SfcS {
  float xs[SEQ_][132];
  float qkv[SEQ_][388];
  float scs[4][SEQ_][19];
  float sinb[SEQ_][32];
  float ffh[SEQ_][8];
  float maskv[SEQ_];
};

__device__ __forceinline__ void par_ln(SfcS& S, const float* __restrict__ lw,
                                       const float* __restrict__ lb, int w, int lane) {
  float w0 = lw[lane * 2], w1 = lw[lane * 2 + 1];
  float b0 = lb[lane * 2], b1 = lb[lane * 2 + 1];
  for (int r = w; r < SEQ_; r += 4) {
    float2 v = *(const float2*)&S.qkv[r][128 + lane * 2];
    float s1 = v.x + v.y;
    float s2 = v.x * v.x + v.y * v.y;
#pragma unroll
    for (int off = 1; off < 64; off <<= 1) {
      s1 += __shfl_xor(s1, off);
      s2 += __shfl_xor(s2, off);
    }
    float mu = s1 * 0.0078125f;
    float var = s2 * 0.0078125f - mu * mu;
    float rsd = rsqrtf(var + 1e-5f);
    S.xs[r][lane * 2]     = (v.x - mu) * rsd * w0 + b0;
    S.xs[r][lane * 2 + 1] = (v.y - mu) * rsd * w1 + b1;
  }
}

__device__ void sfc_body(
    int b, SfcS& S,
    const float* __restrict__ sfc_state, const int* __restrict__ node_pair,
    const float* __restrict__ node_embed, const float* __restrict__ sfcW,
    const float* __restrict__ sfcb, const float* __restrict__ pos,
    const float* __restrict__ qkvW, const float* __restrict__ qkvB,
    const float* __restrict__ outW, const float* __restrict__ outB,
    const float* __restrict__ ln1w, const float* __restrict__ ln1b,
    const float* __restrict__ l1w, const float* __restrict__ l1b,
    const float* __restrict__ l2w, const float* __restrict__ l2b,
    const float* __restrict__ ln2w, const float* __restrict__ ln2b,
    float* __restrict__ out) {
  const int t = threadIdx.x;
  const int w = t >> 6, lane = t & 63;

  for (int i = t; i < SEQ_ * 32; i += 256) {
    int s = i >> 5, d = i & 31;
    float v;
    if (s == 0)       v = node_embed[node_pair[b * 2 + 0] * 32 + d];
    else if (s == 17) v = node_embed[node_pair[b * 2 + 1] * 32 + d];
    else              v = sfc_state[((size_t)b * 16 + (s - 1)) * 32 + d];
    S.sinb[s][d] = v;
  }
  __syncthreads();
  if (t < SEQ_) {
    float sum = 0.f;
#pragma unroll
    for (int d = 0; d < 32; ++d) sum += fabsf(S.sinb[t][d]);
    S.maskv[t] = (sum == 0.f) ? -1e9f : 0.f;
  }
  {
    int hh = t & 127, half = t >> 7;
    f32x4 wr[8];
#pragma unroll
    for (int j = 0; j < 8; ++j) wr[j] = *(const f32x4*)(sfcW + hh * 32 + j * 4);
    for (int si = half * 9; si < half * 9 + 9; ++si) {
      f32x4 a = {0.f, 0.f, 0.f, 0.f};
#pragma unroll
      for (int j = 0; j < 8; ++j) a += wr[j] * (*(const f32x4*)&S.sinb[si][j * 4]);
      S.xs[si][hh] = hadd4(a) + sfcb[hh] + pos[si * HID_ + hh];
    }
  }
  __syncthreads();

  for (int ll = 0; ll < 2; ++ll) {
    for (int oo = t; oo < 384; oo += 256) {
      const float* wp = qkvW + ((size_t)ll * 384 + oo) * HID_;
      float acc[SEQ_];
#pragma unroll
      for (int s = 0; s < SEQ_; ++s) acc[s] = 0.f;
      for (int kb = 0; kb < 4; ++kb) {
        f32x4 wv[8];
#pragma unroll
        for (int j = 0; j < 8; ++j) wv[j] = *(const f32x4*)(wp + kb * 32 + j * 4);
#pragma unroll
        for (int s = 0; s < SEQ_; ++s) {
          f32x4 a = {0.f, 0.f, 0.f, 0.f};
#pragma unroll
          for (int j = 0; j < 8; ++j) a += wv[j] * (*(const f32x4*)&S.xs[s][kb * 32 + j * 4]);
          acc[s] += hadd4(a);
        }
      }
      float bias = qkvB[ll * 384 + oo];
#pragma unroll
      for (int s = 0; s < SEQ_; ++s) S.qkv[s][oo] = acc[s] + bias;
    }
    __syncthreads();
    for (int i = t; i < 4 * SEQ_ * SEQ_; i += 256) {
      int hh = i / (SEQ_ * SEQ_), rem = i - hh * SEQ_ * SEQ_;
      int qi = rem / SEQ_, kj = rem - qi * SEQ_;
      f32x4 a = {0.f, 0.f, 0.f, 0.f};
#pragma unroll
      for (int j = 0; j < 8; ++j)
        a += (*(const f32x4*)&S.qkv[qi][hh * 32 + j * 4]) *
             (*(const f32x4*)&S.qkv[kj][128 + hh * 32 + j * 4]);
      S.scs[hh][qi][kj] = hadd4(a) * 0.17677669529663687f + S.maskv[kj];
    }
    __syncthreads();
    if (t < 4 * SEQ_) {
      int hh = t / SEQ_, qi = t - hh * SEQ_;
      float mx = -1e30f;
#pragma unroll
      for (int j = 0; j < SEQ_; ++j) mx = fmaxf(mx, S.scs[hh][qi][j]);
      float sum = 0.f;
#pragma unroll
      for (int j = 0; j < SEQ_; ++j) {
        float e = __expf(S.scs[hh][qi][j] - mx);
        S.scs[hh][qi][j] = e; sum += e;
      }
      float inv = 1.f / sum;
#pragma unroll
      for (int j = 0; j < SEQ_; ++j) S.scs[hh][qi][j] *= inv;
    }
    __syncthreads();
    for (int i = t; i < SEQ_ * HID_; i += 256) {
      int s = i >> 7, hd = i & 127, hh = hd >> 5;
      float a = 0.f;
#pragma unroll
      for (int j = 0; j < SEQ_; ++j) a += S.scs[hh][s][j] * S.qkv[j][256 + hd];
      S.qkv[s][hd] = a;
    }
    __syncthreads();
    {
      int hh = t & 127, half = t >> 7;
      const float* wp = outW + ((size_t)ll * HID_ + hh) * HID_;
      float acc2[9];
#pragma unroll
      for (int si = 0; si < 9; ++si) acc2[si] = 0.f;
      for (int kb = 0; kb < 4; ++kb) {
        f32x4 wv[8];
#pragma unroll
        for (int j = 0; j < 8; ++j) wv[j] = *(const f32x4*)(wp + kb * 32 + j * 4);
#pragma unroll
        for (int si = 0; si < 9; ++si) {
          int s = half * 9 + si;
          f32x4 a = {0.f, 0.f, 0.f, 0.f};
#pragma unroll
          for (int j = 0; j < 8; ++j) a += wv[j] * (*(const f32x4*)&S.qkv[s][kb * 32 + j * 4]);
          acc2[si] += hadd4(a);
        }
      }
      float bias = outB[ll * HID_ + hh];
#pragma unroll
      for (int si = 0; si < 9; ++si) {
        int s = half * 9 + si;
        S.qkv[s][128 + hh] = S.xs[s][hh] + acc2[si] + bias;
      }
    }
    __syncthreads();
    par_ln(S, ln1w + ll * HID_, ln1b + ll * HID_, w, lane);
    __syncthreads();
    if (t < SEQ_ * 8) {
      int s = t >> 3, oo = t & 7;
      const float* wp = l1w + ((size_t)ll * 8 + oo) * HID_;
      f32x4 a = {0.f, 0.f, 0.f, 0.f};
#pragma unroll
      for (int j = 0; j < 32; ++j)
        a += (*(const f32x4*)(wp + j * 4)) * (*(const f32x4*)&S.xs[s][j * 4]);
      S.ffh[s][oo] = fmaxf(hadd4(a) + l1b[ll * 8 + oo], 0.f);
    }
    __syncthreads();
    for (int i = t; i < SEQ_ * HID_; i += 256) {
      int s = i >> 7, h2 = i & 127;
      const float* wp = l2w + ((size_t)ll * HID_ + h2) * 8;
      float a = 0.f;
#pragma unroll
      for (int j = 0; j < 8; ++j) a += wp[j] * S.ffh[s][j];
      S.qkv[s][128 + h2] = S.xs[s][h2] + a + l2b[ll * HID_ + h2];
    }
    __syncthreads();
    par_ln(S, ln2w + ll * HID_, ln2b + ll * HID_, w, lane);
    __syncthreads();
  }
  for (int i = t; i < SEQ_ * HID_; i += 256) {
    int s = i >> 7, h2 = i & 127;
    out[((size_t)b * OUTR + 2048 + s) * HID_ + h2] = S.xs[s][h2];
  }
}

union ASmem { char attn[32768]; SfcS sfc; };

// ======================= attn (+concurrent sfc blocks 0..15) =======================
__global__ __launch_bounds__(256, 2) void attn_sfc_kernel(
    const short* __restrict__ Qb, const short* __restrict__ Kb,
    const short* __restrict__ Gf, const float* __restrict__ netb,
    const float* __restrict__ sfc_state, const int* __restrict__ node_pair,
    const float* __restrict__ node_embed, const float* __restrict__ sfcW,
    const float* __restrict__ sfcb, const float* __restrict__ pos,
    const float* __restrict__ qkvW, const float* __restrict__ qkvB,
    const float* __restrict__ outW, const float* __restrict__ outB,
    const float* __restrict__ ln1w, const float* __restrict__ ln1b,
    const float* __restrict__ l1w, const float* __restrict__ l1b,
    const float* __restrict__ l2w, const float* __restrict__ l2b,
    const float* __restrict__ ln2w, const float* __restrict__ ln2b,
    float* __restrict__ out) {
  __shared__ ASmem sm;
  if (blockIdx.x < 16) {
    sfc_body(blockIdx.x, sm.sfc, sfc_state, node_pair, node_embed, sfcW, sfcb, pos,
             qkvW, qkvB, outW, outB, ln1w, ln1b, l1w, l1b, l2w, l2b, ln2w, ln2b, out);
    return;
  }
  const int i = blockIdx.x - 16;
  const int b = (i & 7) * 2 + ((i >> 3) & 1);   // batch <-> XCD affinity
  const int q0 = (i >> 4) * 128;
  const int t = threadIdx.x;
  const int w = t >> 6, l = t & 63;
  const int l31 = l & 31, h = l >> 5, l7 = l & 7;
  const int qw = q0 + w * 32;
  const bool hb = (h != 0);

  const short* Kg = Kb + (size_t)b * N_ * DQ;
  char* kb0 = sm.attn;
  char* kb1 = sm.attn + 16384;

  bf16x8 qf[16];
  const short* Qrow = Qb + ((size_t)b * N_ + qw + l31) * DQ + h * 8;
#pragma unroll
  for (int kc = 0; kc < 16; ++kc)
    qf[kc] = *(const bf16x8*)(Qrow + kc * 16);

  f32x16 o[4];
#pragma unroll
  for (int dt = 0; dt < 4; ++dt)
#pragma unroll
    for (int r = 0; r < 16; ++r) o[dt][r] = 0.f;
  float lsum = 0.f;

  auto stage_k = [&](int tile, char* dst) {
#pragma unroll
    for (int it = 0; it < 4; ++it) {
      int idx = w * 4 + it;
      int row = idx * 2 + h;
      int gcol = (l31 * 16) ^ ((row & 7) << 4);
      const char* src = (const char*)(Kg + (size_t)(tile * KVB + row) * DQ) + gcol;
      __builtin_amdgcn_global_load_lds(
          (const __attribute__((address_space(1))) void*)src,
          (__attribute__((address_space(3))) void*)(dst + idx * 1024), 16, 0, 0);
    }
  };

  stage_k(0, kb0);
  __syncthreads();

  const short* Gb = Gf + (size_t)b * 64 * 4096;
  for (int tt = 0; tt < 64; ++tt) {
    char* kc_ = (tt & 1) ? kb1 : kb0;
    if (tt < 63) stage_k(tt + 1, (tt & 1) ? kb0 : kb1);
    // prefetch G frags for this tile (L1/L2): vw[dt*2+half]
    const short* gt = Gb + (size_t)tt * 4096 + l * 8;
    bf16x8 vw[8];
#pragma unroll
    for (int f = 0; f < 8; ++f)
      vw[f] = *(const bf16x8*)(gt + f * 512);
    // QK^T (swapped: S^T[32 kv][32 q], q lane-local)
    f32x16 s;
#pragma unroll
    for (int r = 0; r < 16; ++r) s[r] = 0.f;
    __builtin_amdgcn_s_setprio(1);
#pragma unroll
    for (int kc = 0; kc < 16; ++kc) {
      bf16x8 kf = *(const bf16x8*)(kc_ + l31 * 512 + ((kc * 32 + h * 16) ^ (l7 << 4)));
      s = __builtin_amdgcn_mfma_f32_32x32x16_bf16(kf, qf[kc], s, 0, 0, 0);
    }
    __builtin_amdgcn_s_setprio(0);
    // softmax m=0 (|scores| bounded; exact) -> in-register P fragments
#pragma unroll
    for (int r = 0; r < 16; ++r) { s[r] = __expf(s[r]); lsum += s[r]; }
    unsigned wA = cvtpk(s[0], s[1]),   wB = cvtpk(s[2], s[3]);
    unsigned wC = cvtpk(s[4], s[5]),   wD = cvtpk(s[6], s[7]);
    unsigned wE = cvtpk(s[8], s[9]),   wF = cvtpk(s[10], s[11]);
    unsigned wG = cvtpk(s[12], s[13]), wH = cvtpk(s[14], s[15]);
    bf16x8 pf0 = mkfrag(wA, wB, wC, wD, hb);
    bf16x8 pf1 = mkfrag(wE, wF, wG, wH, hb);
    // P·G: O[128 d'][32 q]
    __builtin_amdgcn_s_setprio(1);
#pragma unroll
    for (int dt = 0; dt < 4; ++dt) {
      o[dt] = __builtin_amdgcn_mfma_f32_32x32x16_bf16(vw[dt * 2],     pf0, o[dt], 0, 0, 0);
      o[dt] = __builtin_amdgcn_mfma_f32_32x32x16_bf16(vw[dt * 2 + 1], pf1, o[dt], 0, 0, 0);
    }
    __builtin_amdgcn_s_setprio(0);
    __syncthreads();       // drains next-tile staging + all waves done with kc_
  }

  lsum += __shfl_xor(lsum, 32);
  const float linv = 1.f / lsum;

  // epilogue: out = O·linv + netb  (already projected to HID=128)
  float* orow = out + ((size_t)b * OUTR + qw + l31) * HID_;
#pragma unroll
  for (int dt = 0; dt < 4; ++dt) {
#pragma unroll
    for (int rq = 0; rq < 4; ++rq) {
      f32x4 bia = *(const f32x4*)(netb + dt * 32 + rq * 8 + h * 4);
      f32x4 vv;
      vv[0] = o[dt][4 * rq + 0] * linv + bia[0];
      vv[1] = o[dt][4 * rq + 1] * linv + bia[1];
      vv[2] = o[dt][4 * rq + 2] * linv + bia[2];
      vv[3] = o[dt][4 * rq + 3] * linv + bia[3];
      *(f32x4*)(orow + dt * 32 + rq * 8 + h * 4) = vv;
    }
  }
}

extern "C" void kernel_launch(void* const* d_in, const int* in_sizes, int n_in,
                              void* d_out, int out_size, void* d_ws, size_t ws_size,
                              hipStream_t stream) {
  (void)in_sizes; (void)n_in; (void)out_size; (void)ws_size;
  const float* net_state  = (const float*)d_in[0];
  const float* sfc_state  = (const float*)d_in[1];
  const int*   node_pair  = (const int*)d_in[2];
  const float* Wq   = (const float*)d_in[3];
  const float* bq   = (const float*)d_in[4];
  const float* Wk   = (const float*)d_in[5];
  const float* bk   = (const float*)d_in[6];
  const float* Wv   = (const float*)d_in[7];
  const float* bv   = (const float*)d_in[8];
  const float* netW = (const float*)d_in[9];
  const float* netb = (const float*)d_in[10];
  const float* node_embed = (const float*)d_in[11];
  const float* sfcW = (const float*)d_in[12];
  const float* sfcb = (const float*)d_in[13];
  const float* pos  = (const float*)d_in[14];
  const float* qkvW = (const float*)d_in[15];
  const float* qkvB = (const float*)d_in[16];
  const float* outW = (const float*)d_in[17];
  const float* outB = (const float*)d_in[18];
  const float* ln1w = (const float*)d_in[19];
  const float* ln1b = (const float*)d_in[20];
  const float* l1w  = (const float*)d_in[21];
  const float* l1b  = (const float*)d_in[22];
  const float* l2w  = (const float*)d_in[23];
  const float* l2b  = (const float*)d_in[24];
  const float* ln2w = (const float*)d_in[25];
  const float* ln2b = (const float*)d_in[26];
  float* out = (float*)d_out;

  const size_t S = (size_t)B_ * N_ * DQ;       // 8,388,608 shorts
  short* Qb = (short*)d_ws;
  short* Kb = Qb + S;
  short* Gf = Kb + S;                          // 16 b x 64 nt x 8 frag x 512 = 4M shorts

  proj_kernel<<<256, 512, 0, stream>>>(net_state, Wq, bq, Wk, bk, Wv, bv, netW, Qb, Kb, Gf);
  attn_sfc_kernel<<<272, 256, 0, stream>>>(Qb, Kb, Gf, netb,
                                           sfc_state, node_pair, node_embed, sfcW, sfcb, pos,
                                           qkvW, qkvB, outW, outB, ln1w, ln1b, l1w, l1b,
                                           l2w, l2b, ln2w, ln2b, out);
}

// Round 8
// 127.029 us; speedup vs baseline: 3.2094x; 1.4516x over previous
//
#include <hip/hip_runtime.h>
#include <cstdint>
#include <cstddef>

#define B_   16
#define N_   2048
#define DN   64
#define DQ   256     // 4*D_NET
#define HID_ 128
#define SEQ_ 18
#define OUTR 2066
#define KVB  32

typedef __attribute__((ext_vector_type(4)))  float f32x4;
typedef __attribute__((ext_vector_type(16))) float f32x16;
typedef __attribute__((ext_vector_type(8)))  short bf16x8;

__device__ __forceinline__ unsigned cvtpk(float lo, float hi) {
  unsigned w;
  asm("v_cvt_pk_bf16_f32 %0, %1, %2" : "=v"(w) : "v"(lo), "v"(hi));
  return w;
}
__device__ __forceinline__ short f2bf(float f) {
  union { float f; unsigned u; } v; v.f = f;
  unsigned r = v.u + 0x7fffu + ((v.u >> 16) & 1u);
  return (short)(r >> 16);
}
__device__ __forceinline__ bf16x8 cvt8(const float* p) {
  f32x4 a = *(const f32x4*)p, b = *(const f32x4*)(p + 4);
  union { unsigned u[4]; bf16x8 v; } r;
  r.u[0] = cvtpk(a[0], a[1]); r.u[1] = cvtpk(a[2], a[3]);
  r.u[2] = cvtpk(b[0], b[1]); r.u[3] = cvtpk(b[2], b[3]);
  return r.v;
}
__device__ __forceinline__ float hadd4(f32x4 v) { return (v[0] + v[1]) + (v[2] + v[3]); }

// redistribute 32x32 C-layout rows into MFMA-fragment k-order (A or B frag)
__device__ __forceinline__ bf16x8 mkfrag(unsigned wa, unsigned wb,
                                         unsigned wc, unsigned wd, bool hi) {
  unsigned sa = (unsigned)__shfl_xor((int)wa, 32);
  unsigned sb = (unsigned)__shfl_xor((int)wb, 32);
  unsigned sc = (unsigned)__shfl_xor((int)wc, 32);
  unsigned sd = (unsigned)__shfl_xor((int)wd, 32);
  union { unsigned u[4]; bf16x8 v; } r;
  r.u[0] = hi ? sc : wa;
  r.u[1] = hi ? sd : wb;
  r.u[2] = hi ? wc : sa;
  r.u[3] = hi ? wd : sb;
  return r.v;
}

// ======================= proj kernel: Q, K, and G = netW·V^T frags =======================
__global__ __launch_bounds__(512) void proj_kernel(
    const float* __restrict__ net, const float* __restrict__ Wq, const float* __restrict__ bq,
    const float* __restrict__ Wk, const float* __restrict__ bk,
    const float* __restrict__ Wv, const float* __restrict__ bv,
    const float* __restrict__ netW,
    short* __restrict__ Qb, short* __restrict__ Kb, short* __restrict__ Gf) {
  __shared__ char psm[98304];          // wl 32KB | Vrm 64KB (bf16 [128 n][256 d] swizzled)
  short* wl = (short*)psm;
  char* vrm = psm + 32768;

  const int gid = blockIdx.x;
  const int b = gid >> 4;
  const int r0 = (gid & 15) * 128;
  const int t = threadIdx.x;
  const int w = t >> 6, lane = t & 63, ln = lane & 15, g = lane >> 4;
  const int rw = r0 + w * 16;
  const int xk = (ln & 7) << 4;

  bf16x8 af[2];
#pragma unroll
  for (int c = 0; c < 2; ++c)
    af[c] = cvt8(net + ((size_t)b * N_ + rw + ln) * DN + c * 32 + g * 8);

  const float* Ws[3] = {Wq, Wk, Wv};
  for (int m = 0; m < 3; ++m) {
    __syncthreads();
#pragma unroll
    for (int it = 0; it < 8; ++it) {         // stage W[m] 256x64 f32 -> bf16 swizzled
      int idx = it * 512 + t;
      int row = idx >> 4, c8 = idx & 15;
      f32x4 v = *(const f32x4*)(Ws[m] + row * 64 + c8 * 4);
      int byo = row * 128 + ((c8 * 8) ^ ((row & 7) << 4));
      *(uint2*)((char*)wl + byo) = make_uint2(cvtpk(v[0], v[1]), cvtpk(v[2], v[3]));
    }
    __syncthreads();
    if (m < 2) {
      const float* bias = (m == 0) ? bq : bk;
      short* dst = (m == 0) ? Qb : Kb;
      const float sc = (m == 0) ? 0.125f : 1.0f;   // fold 1/sqrt(64) into Q
#pragma unroll
      for (int tt = 0; tt < 16; ++tt) {
        f32x4 acc = {0.f, 0.f, 0.f, 0.f};
#pragma unroll
        for (int c = 0; c < 2; ++c) {
          int byo = (tt * 16 + ln) * 128 + ((c * 64 + g * 16) ^ xk);
          bf16x8 wf = *(const bf16x8*)((char*)wl + byo);
          acc = __builtin_amdgcn_mfma_f32_16x16x32_bf16(wf, af[c], acc, 0, 0, 0);
        }
        f32x4 b4 = *(const f32x4*)(bias + tt * 16 + g * 4);
        uint2 u = make_uint2(cvtpk((acc[0] + b4[0]) * sc, (acc[1] + b4[1]) * sc),
                             cvtpk((acc[2] + b4[2]) * sc, (acc[3] + b4[3]) * sc));
        *(uint2*)(dst + ((size_t)b * N_ + rw + ln) * DQ + tt * 16 + g * 4) = u;
      }
    } else {
      // V tile -> bf16 row-major in LDS (Vrm[nn][d], 512B rows, XOR swizzle)
#pragma unroll
      for (int tt = 0; tt < 16; ++tt) {
        f32x4 acc = {0.f, 0.f, 0.f, 0.f};
#pragma unroll
        for (int c = 0; c < 2; ++c) {
          int byo = (tt * 16 + ln) * 128 + ((c * 64 + g * 16) ^ xk);
          bf16x8 wf = *(const bf16x8*)((char*)wl + byo);
          acc = __builtin_amdgcn_mfma_f32_16x16x32_bf16(af[c], wf, acc, 0, 0, 0);
        }
        float bias = bv[tt * 16 + ln];
        int d = tt * 16 + ln;
#pragma unroll
        for (int r = 0; r < 4; ++r) {
          int nn = w * 16 + g * 4 + r;
          int byte = nn * 512 + ((d * 2) ^ ((nn & 7) << 4));
          *(short*)(vrm + byte) = f2bf(acc[r] + bias);
        }
      }
    }
  }
  __syncthreads();

  // ---- G phase: G^T tiles C[n][d'] = V[n][:]·netW[d'][:]; mkfrag -> PV A-frags ----
  const int l31 = lane & 31, h = lane >> 5;
  const bool hb = (h != 0);
#pragma unroll
  for (int j = 0; j < 2; ++j) {
    int ti = w * 2 + j;
    int nt = ti >> 2, dt = ti & 3;
    f32x16 C;
#pragma unroll
    for (int r = 0; r < 16; ++r) C[r] = 0.f;
    int n = nt * 32 + l31;
#pragma unroll
    for (int dc = 0; dc < 16; ++dc) {
      bf16x8 A = *(const bf16x8*)(vrm + n * 512 + ((dc * 32 + h * 16) ^ ((n & 7) << 4)));
      bf16x8 Bf = cvt8(netW + (size_t)(dt * 32 + l31) * DQ + dc * 16 + h * 8);
      C = __builtin_amdgcn_mfma_f32_32x32x16_bf16(A, Bf, C, 0, 0, 0);
    }
    unsigned a0 = cvtpk(C[0],  C[1]),  a1 = cvtpk(C[2],  C[3]);
    unsigned a2 = cvtpk(C[4],  C[5]),  a3 = cvtpk(C[6],  C[7]);
    unsigned a4 = cvtpk(C[8],  C[9]),  a5 = cvtpk(C[10], C[11]);
    unsigned a6 = cvtpk(C[12], C[13]), a7 = cvtpk(C[14], C[15]);
    bf16x8 f0 = mkfrag(a0, a1, a2, a3, hb);   // k = n 0..15
    bf16x8 f1 = mkfrag(a4, a5, a6, a7, hb);   // k = n 16..31
    size_t base = (((size_t)b * 64 + (r0 >> 5) + nt) * 8 + dt * 2) * 512;
    *(bf16x8*)(Gf + base + lane * 8)       = f0;
    *(bf16x8*)(Gf + base + 512 + lane * 8) = f1;
  }
}

// ======================= sfc (MFMA qkv/outproj) =======================
struct SfcS {
  float xs[SEQ_][132];
  float qkv[SEQ_][388];
  float scs[4][SEQ_][19];
  float sinb[SEQ_][32];
  float ffh[SEQ_][8];
  float maskv[SEQ_];
  short xbf[32 * 128];     // bf16 mirror [32][128], XOR-swizzled, rows 18..31 zero
};

__device__ __forceinline__ void par_ln(SfcS& S, const float* __restrict__ lw,
                                       const float* __restrict__ lb, int w, int lane) {
  float w0 = lw[lane * 2], w1 = lw[lane * 2 + 1];
  float b0 = lb[lane * 2], b1 = lb[lane * 2 + 1];
  for (int r = w; r < SEQ_; r += 4) {
    float2 v = *(const float2*)&S.qkv[r][128 + lane * 2];
    float s1 = v.x + v.y;
    float s2 = v.x * v.x + v.y * v.y;
#pragma unroll
    for (int off = 1; off < 64; off <<= 1) {
      s1 += __shfl_xor(s1, off);
      s2 += __shfl_xor(s2, off);
    }
    float mu = s1 * 0.0078125f;
    float var = s2 * 0.0078125f - mu * mu;
    float rsd = rsqrtf(var + 1e-5f);
    S.xs[r][lane * 2]     = (v.x - mu) * rsd * w0 + b0;
    S.xs[r][lane * 2 + 1] = (v.y - mu) * rsd * w1 + b1;
  }
}

// copy rows[0..17] of f32 matrix (stride) into swizzled bf16 [32][128] tile
__device__ __forceinline__ void rows_to_bf(const float* __restrict__ src, int stride,
                                           char* __restrict__ xbf, int t) {
  for (int i = t; i < SEQ_ * 16; i += 256) {
    int row = i >> 4, c8 = i & 15;
    const float* p = src + row * stride + c8 * 8;
    f32x4 a = *(const f32x4*)p;
    f32x4 b = *(const f32x4*)(p + 4);
    uint4 u;
    u.x = cvtpk(a[0], a[1]); u.y = cvtpk(a[2], a[3]);
    u.z = cvtpk(b[0], b[1]); u.w = cvtpk(b[2], b[3]);
    int byo = row * 256 + ((c8 * 16) ^ ((row & 7) << 4));
    *(uint4*)(xbf + byo) = u;
  }
}

__device__ void sfc_body(
    int b, SfcS& S,
    const float* __restrict__ sfc_state, const int* __restrict__ node_pair,
    const float* __restrict__ node_embed, const float* __restrict__ sfcW,
    const float* __restrict__ sfcb, const float* __restrict__ pos,
    const float* __restrict__ qkvW, const float* __restrict__ qkvB,
    const float* __restrict__ outW, const float* __restrict__ outB,
    const float* __restrict__ ln1w, const float* __restrict__ ln1b,
    const float* __restrict__ l1w, const float* __restrict__ l1b,
    const float* __restrict__ l2w, const float* __restrict__ l2b,
    const float* __restrict__ ln2w, const float* __restrict__ ln2b,
    float* __restrict__ out) {
  const int t = threadIdx.x;
  const int w = t >> 6, lane = t & 63, ln = lane & 15, g = lane >> 4;
  char* xbf = (char*)S.xbf;
  const int xk2 = (ln & 7) << 4;

  // zero the bf16 tile once (rows 18..31 stay zero forever)
  for (int i = t; i < 512; i += 256) ((uint4*)xbf)[i] = make_uint4(0, 0, 0, 0);

  for (int i = t; i < SEQ_ * 32; i += 256) {
    int s = i >> 5, d = i & 31;
    float v;
    if (s == 0)       v = node_embed[node_pair[b * 2 + 0] * 32 + d];
    else if (s == 17) v = node_embed[node_pair[b * 2 + 1] * 32 + d];
    else              v = sfc_state[((size_t)b * 16 + (s - 1)) * 32 + d];
    S.sinb[s][d] = v;
  }
  __syncthreads();
  if (t < SEQ_) {
    float sum = 0.f;
#pragma unroll
    for (int d = 0; d < 32; ++d) sum += fabsf(S.sinb[t][d]);
    S.maskv[t] = (sum == 0.f) ? -1e9f : 0.f;
  }
  {
    int hh = t & 127, half = t >> 7;
    f32x4 wr[8];
#pragma unroll
    for (int j = 0; j < 8; ++j) wr[j] = *(const f32x4*)(sfcW + hh * 32 + j * 4);
    for (int si = half * 9; si < half * 9 + 9; ++si) {
      f32x4 a = {0.f, 0.f, 0.f, 0.f};
#pragma unroll
      for (int j = 0; j < 8; ++j) a += wr[j] * (*(const f32x4*)&S.sinb[si][j * 4]);
      S.xs[si][hh] = hadd4(a) + sfcb[hh] + pos[si * HID_ + hh];
    }
  }
  __syncthreads();

  for (int ll = 0; ll < 2; ++ll) {
    // --- x -> bf16 tile ---
    rows_to_bf(&S.xs[0][0], 132, xbf, t);
    __syncthreads();
    // --- qkv = x @ W^T + b : MFMA, 6 N-tiles/wave ---
    {
      bf16x8 af[2][4];
#pragma unroll
      for (int m = 0; m < 2; ++m)
#pragma unroll
        for (int k = 0; k < 4; ++k)
          af[m][k] = *(const bf16x8*)(xbf + (m * 16 + ln) * 256 + ((k * 64 + g * 16) ^ xk2));
#pragma unroll
      for (int i = 0; i < 6; ++i) {
        int nt = w + i * 4;
        const float* wp = qkvW + ((size_t)ll * 384 + nt * 16 + ln) * HID_;
        f32x4 a0 = {0.f, 0.f, 0.f, 0.f}, a1 = {0.f, 0.f, 0.f, 0.f};
#pragma unroll
        for (int k = 0; k < 4; ++k) {
          bf16x8 wf = cvt8(wp + k * 32 + g * 8);
          a0 = __builtin_amdgcn_mfma_f32_16x16x32_bf16(wf, af[0][k], a0, 0, 0, 0);
          a1 = __builtin_amdgcn_mfma_f32_16x16x32_bf16(wf, af[1][k], a1, 0, 0, 0);
        }
        f32x4 b4 = *(const f32x4*)(qkvB + ll * 384 + nt * 16 + g * 4);
#pragma unroll
        for (int r = 0; r < 4; ++r) {
          S.qkv[ln][nt * 16 + g * 4 + r] = a0[r] + b4[r];
          if (ln < 2) S.qkv[16 + ln][nt * 16 + g * 4 + r] = a1[r] + b4[r];
        }
      }
    }
    __syncthreads();
    // --- scores ---
    for (int i = t; i < 4 * SEQ_ * SEQ_; i += 256) {
      int hh = i / (SEQ_ * SEQ_), rem = i - hh * SEQ_ * SEQ_;
      int qi = rem / SEQ_, kj = rem - qi * SEQ_;
      f32x4 a = {0.f, 0.f, 0.f, 0.f};
#pragma unroll
      for (int j = 0; j < 8; ++j)
        a += (*(const f32x4*)&S.qkv[qi][hh * 32 + j * 4]) *
             (*(const f32x4*)&S.qkv[kj][128 + hh * 32 + j * 4]);
      S.scs[hh][qi][kj] = hadd4(a) * 0.17677669529663687f + S.maskv[kj];
    }
    __syncthreads();
    // --- softmax rows ---
    if (t < 4 * SEQ_) {
      int hh = t / SEQ_, qi = t - hh * SEQ_;
      float mx = -1e30f;
#pragma unroll
      for (int j = 0; j < SEQ_; ++j) mx = fmaxf(mx, S.scs[hh][qi][j]);
      float sum = 0.f;
#pragma unroll
      for (int j = 0; j < SEQ_; ++j) {
        float e = __expf(S.scs[hh][qi][j] - mx);
        S.scs[hh][qi][j] = e; sum += e;
      }
      float inv = 1.f / sum;
#pragma unroll
      for (int j = 0; j < SEQ_; ++j) S.scs[hh][qi][j] *= inv;
    }
    __syncthreads();
    // --- attn @ v -> q-region of qkv ---
    for (int i = t; i < SEQ_ * HID_; i += 256) {
      int s = i >> 7, hd = i & 127, hh = hd >> 5;
      float a = 0.f;
#pragma unroll
      for (int j = 0; j < SEQ_; ++j) a += S.scs[hh][s][j] * S.qkv[j][256 + hd];
      S.qkv[s][hd] = a;
    }
    __syncthreads();
    // --- att -> bf16 tile ---
    rows_to_bf(&S.qkv[0][0], 388, xbf, t);
    __syncthreads();
    // --- out-proj + residual -> k-region : MFMA, 2 N-tiles/wave ---
    {
      bf16x8 af[2][4];
#pragma unroll
      for (int m = 0; m < 2; ++m)
#pragma unroll
        for (int k = 0; k < 4; ++k)
          af[m][k] = *(const bf16x8*)(xbf + (m * 16 + ln) * 256 + ((k * 64 + g * 16) ^ xk2));
#pragma unroll
      for (int i = 0; i < 2; ++i) {
        int nt = w + i * 4;
        const float* wp = outW + ((size_t)ll * HID_ + nt * 16 + ln) * HID_;
        f32x4 a0 = {0.f, 0.f, 0.f, 0.f}, a1 = {0.f, 0.f, 0.f, 0.f};
#pragma unroll
        for (int k = 0; k < 4; ++k) {
          bf16x8 wf = cvt8(wp + k * 32 + g * 8);
          a0 = __builtin_amdgcn_mfma_f32_16x16x32_bf16(wf, af[0][k], a0, 0, 0, 0);
          a1 = __builtin_amdgcn_mfma_f32_16x16x32_bf16(wf, af[1][k], a1, 0, 0, 0);
        }
        f32x4 b4 = *(const f32x4*)(outB + ll * HID_ + nt * 16 + g * 4);
#pragma unroll
        for (int r = 0; r < 4; ++r) {
          int h = nt * 16 + g * 4 + r;
          S.qkv[ln][128 + h] = S.xs[ln][h] + a0[r] + b4[r];
          if (ln < 2) S.qkv[16 + ln][128 + h] = S.xs[16 + ln][h] + a1[r] + b4[r];
        }
      }
    }
    __syncthreads();
    par_ln(S, ln1w + ll * HID_, ln1b + ll * HID_, w, lane);
    __syncthreads();
    if (t < SEQ_ * 8) {
      int s = t >> 3, oo = t & 7;
      const float* wp = l1w + ((size_t)ll * 8 + oo) * HID_;
      f32x4 a = {0.f, 0.f, 0.f, 0.f};
#pragma unroll
      for (int j = 0; j < 32; ++j)
        a += (*(const f32x4*)(wp + j * 4)) * (*(const f32x4*)&S.xs[s][j * 4]);
      S.ffh[s][oo] = fmaxf(hadd4(a) + l1b[ll * 8 + oo], 0.f);
    }
    __syncthreads();
    for (int i = t; i < SEQ_ * HID_; i += 256) {
      int s = i >> 7, h2 = i & 127;
      const float* wp = l2w + ((size_t)ll * HID_ + h2) * 8;
      float a = 0.f;
#pragma unroll
      for (int j = 0; j < 8; ++j) a += wp[j] * S.ffh[s][j];
      S.qkv[s][128 + h2] = S.xs[s][h2] + a + l2b[ll * HID_ + h2];
    }
    __syncthreads();
    par_ln(S, ln2w + ll * HID_, ln2b + ll * HID_, w, lane);
    __syncthreads();
  }
  for (int i = t; i < SEQ_ * HID_; i += 256) {
    int s = i >> 7, h2 = i & 127;
    out[((size_t)b * OUTR + 2048 + s) * HID_ + h2] = S.xs[s][h2];
  }
}

union ASmem { char attn[32768]; SfcS sfc; };

// ======================= attn (+concurrent sfc blocks 0..15) =======================
__global__ __launch_bounds__(256, 2) void attn_sfc_kernel(
    const short* __restrict__ Qb, const short* __restrict__ Kb,
    const short* __restrict__ Gf, const float* __restrict__ netb,
    const float* __restrict__ sfc_state, const int* __restrict__ node_pair,
    const float* __restrict__ node_embed, const float* __restrict__ sfcW,
    const float* __restrict__ sfcb, const float* __restrict__ pos,
    const float* __restrict__ qkvW, const float* __restrict__ qkvB,
    const float* __restrict__ outW, const float* __restrict__ outB,
    const float* __restrict__ ln1w, const float* __restrict__ ln1b,
    const float* __restrict__ l1w, const float* __restrict__ l1b,
    const float* __restrict__ l2w, const float* __restrict__ l2b,
    const float* __restrict__ ln2w, const float* __restrict__ ln2b,
    float* __restrict__ out) {
  __shared__ ASmem sm;
  if (blockIdx.x < 16) {
    sfc_body(blockIdx.x, sm.sfc, sfc_state, node_pair, node_embed, sfcW, sfcb, pos,
             qkvW, qkvB, outW, outB, ln1w, ln1b, l1w, l1b, l2w, l2b, ln2w, ln2b, out);
    return;
  }
  const int i = blockIdx.x - 16;
  const int b = (i & 7) * 2 + ((i >> 3) & 1);   // batch <-> XCD affinity
  const int q0 = (i >> 4) * 128;
  const int t = threadIdx.x;
  const int w = t >> 6, l = t & 63;
  const int l31 = l & 31, h = l >> 5, l7 = l & 7;
  const int qw = q0 + w * 32;
  const bool hb = (h != 0);

  const short* Kg = Kb + (size_t)b * N_ * DQ;
  char* kb0 = sm.attn;
  char* kb1 = sm.attn + 16384;

  bf16x8 qf[16];
  const short* Qrow = Qb + ((size_t)b * N_ + qw + l31) * DQ + h * 8;
#pragma unroll
  for (int kc = 0; kc < 16; ++kc)
    qf[kc] = *(const bf16x8*)(Qrow + kc * 16);

  f32x16 o[4];
#pragma unroll
  for (int dt = 0; dt < 4; ++dt)
#pragma unroll
    for (int r = 0; r < 16; ++r) o[dt][r] = 0.f;
  float lsum = 0.f;

  auto stage_k = [&](int tile, char* dst) {
#pragma unroll
    for (int it = 0; it < 4; ++it) {
      int idx = w * 4 + it;
      int row = idx * 2 + h;
      int gcol = (l31 * 16) ^ ((row & 7) << 4);
      const char* src = (const char*)(Kg + (size_t)(tile * KVB + row) * DQ) + gcol;
      __builtin_amdgcn_global_load_lds(
          (const __attribute__((address_space(1))) void*)src,
          (__attribute__((address_space(3))) void*)(dst + idx * 1024), 16, 0, 0);
    }
  };

  stage_k(0, kb0);
  __syncthreads();

  const short* Gb = Gf + (size_t)b * 64 * 4096;
  for (int tt = 0; tt < 64; ++tt) {
    char* kc_ = (tt & 1) ? kb1 : kb0;
    if (tt < 63) stage_k(tt + 1, (tt & 1) ? kb0 : kb1);
    // prefetch G frags for this tile (L1/L2): vw[dt*2+half]
    const short* gt = Gb + (size_t)tt * 4096 + l * 8;
    bf16x8 vw[8];
#pragma unroll
    for (int f = 0; f < 8; ++f)
      vw[f] = *(const bf16x8*)(gt + f * 512);
    // QK^T (swapped: S^T[32 kv][32 q], q lane-local)
    f32x16 s;
#pragma unroll
    for (int r = 0; r < 16; ++r) s[r] = 0.f;
    __builtin_amdgcn_s_setprio(1);
#pragma unroll
    for (int kc = 0; kc < 16; ++kc) {
      bf16x8 kf = *(const bf16x8*)(kc_ + l31 * 512 + ((kc * 32 + h * 16) ^ (l7 << 4)));
      s = __builtin_amdgcn_mfma_f32_32x32x16_bf16(kf, qf[kc], s, 0, 0, 0);
    }
    __builtin_amdgcn_s_setprio(0);
    // softmax m=0 (|scores| bounded; exact) -> in-register P fragments
#pragma unroll
    for (int r = 0; r < 16; ++r) { s[r] = __expf(s[r]); lsum += s[r]; }
    unsigned wA = cvtpk(s[0], s[1]),   wB = cvtpk(s[2], s[3]);
    unsigned wC = cvtpk(s[4], s[5]),   wD = cvtpk(s[6], s[7]);
    unsigned wE = cvtpk(s[8], s[9]),   wF = cvtpk(s[10], s[11]);
    unsigned wG = cvtpk(s[12], s[13]), wH = cvtpk(s[14], s[15]);
    bf16x8 pf0 = mkfrag(wA, wB, wC, wD, hb);
    bf16x8 pf1 = mkfrag(wE, wF, wG, wH, hb);
    // P·G: O[128 d'][32 q]
    __builtin_amdgcn_s_setprio(1);
#pragma unroll
    for (int dt = 0; dt < 4; ++dt) {
      o[dt] = __builtin_amdgcn_mfma_f32_32x32x16_bf16(vw[dt * 2],     pf0, o[dt], 0, 0, 0);
      o[dt] = __builtin_amdgcn_mfma_f32_32x32x16_bf16(vw[dt * 2 + 1], pf1, o[dt], 0, 0, 0);
    }
    __builtin_amdgcn_s_setprio(0);
    __syncthreads();       // drains next-tile staging + all waves done with kc_
  }

  lsum += __shfl_xor(lsum, 32);
  const float linv = 1.f / lsum;

  // epilogue: out = O·linv + netb  (already projected to HID=128)
  float* orow = out + ((size_t)b * OUTR + qw + l31) * HID_;
#pragma unroll
  for (int dt = 0; dt < 4; ++dt) {
#pragma unroll
    for (int rq = 0; rq < 4; ++rq) {
      f32x4 bia = *(const f32x4*)(netb + dt * 32 + rq * 8 + h * 4);
      f32x4 vv;
      vv[0] = o[dt][4 * rq + 0] * linv + bia[0];
      vv[1] = o[dt][4 * rq + 1] * linv + bia[1];
      vv[2] = o[dt][4 * rq + 2] * linv + bia[2];
      vv[3] = o[dt][4 * rq + 3] * linv + bia[3];
      *(f32x4*)(orow + dt * 32 + rq * 8 + h * 4) = vv;
    }
  }
}

extern "C" void kernel_launch(void* const* d_in, const int* in_sizes, int n_in,
                              void* d_out, int out_size, void* d_ws, size_t ws_size,
                              hipStream_t stream) {
  (void)in_sizes; (void)n_in; (void)out_size; (void)ws_size;
  const float* net_state  = (const float*)d_in[0];
  const float* sfc_state  = (const float*)d_in[1];
  const int*   node_pair  = (const int*)d_in[2];
  const float* Wq   = (const float*)d_in[3];
  const float* bq   = (const float*)d_in[4];
  const float* Wk   = (const float*)d_in[5];
  const float* bk   = (const float*)d_in[6];
  const float* Wv   = (const float*)d_in[7];
  const float* bv   = (const float*)d_in[8];
  const float* netW = (const float*)d_in[9];
  const float* netb = (const float*)d_in[10];
  const float* node_embed = (const float*)d_in[11];
  const float* sfcW = (const float*)d_in[12];
  const float* sfcb = (const float*)d_in[13];
  const float* pos  = (const float*)d_in[14];
  const float* qkvW = (const float*)d_in[15];
  const float* qkvB = (const float*)d_in[16];
  const float* outW = (const float*)d_in[17];
  const float* outB = (const float*)d_in[18];
  const float* ln1w = (const float*)d_in[19];
  const float* ln1b = (const float*)d_in[20];
  const float* l1w  = (const float*)d_in[21];
  const float* l1b  = (const float*)d_in[22];
  const float* l2w  = (const float*)d_in[23];
  const float* l2b  = (const float*)d_in[24];
  const float* ln2w = (const float*)d_in[25];
  const float* ln2b = (const float*)d_in[26];
  float* out = (float*)d_out;

  const size_t S = (size_t)B_ * N_ * DQ;       // 8,388,608 shorts
  short* Qb = (short*)d_ws;
  short* Kb = Qb + S;
  short* Gf = Kb + S;                          // 16 b x 64 nt x 8 frag x 512 = 4M shorts

  proj_kernel<<<256, 512, 0, stream>>>(net_state, Wq, bq, Wk, bk, Wv, bv, netW, Qb, Kb, Gf);
  attn_sfc_kernel<<<272, 256, 0, stream>>>(Qb, Kb, Gf, netb,
                                           sfc_state, node_pair, node_embed, sfcW, sfcb, pos,
                                           qkvW, qkvB, outW, outB, ln1w, ln1b, l1w, l1b,
                                           l2w, l2b, ln2w, ln2b, out);
}